// Round 8
// baseline (244.545 us; speedup 1.0000x reference)
//
#include <hip/hip_runtime.h>
#include <hip/hip_bf16.h>

// AdaptiveInput on gfx950.
// R7 -> R8: GEMM pipeline deepened to 3 LDS buffers / 2-deep prefetch
// (issue(t+2), s_waitcnt vmcnt(12)): 12 glds in flight spanning two compute
// phases, covering L2 latency that the 1-deep R7 pipeline exposed each step
// (1 block/CU, 2 waves/SIMD -> no TLP to hide it). LDS 144.5 KB (<160 max).
// Rest unchanged: partition, fused gather_cvt+head, bijective XCD swizzle,
// XOR source-swizzled glds, setprio around MFMA.

typedef __attribute__((ext_vector_type(8))) short short8;   // 8 bf16 (MFMA A/B frag)
typedef __attribute__((ext_vector_type(4))) float f32x4;    // MFMA C/D frag
typedef unsigned int u32;
typedef unsigned short u16;

__device__ __forceinline__ u32 pk2bf(float a, float b) {
    __hip_bfloat162 h = __float22bfloat162_rn(make_float2(a, b));   // v_cvt_pk_bf16_f32
    union { __hip_bfloat162 h; u32 u; } c; c.h = h; return c.u;
}

__device__ __forceinline__ void glds16(const void* g, void* l) {
    __builtin_amdgcn_global_load_lds((const __attribute__((address_space(1))) u32*)g,
                                     (__attribute__((address_space(3))) u32*)l, 16, 0, 0);
}

// Block-aggregated partition: 3 atomics per block. Head list descends from top of l1.
__global__ __launch_bounds__(256) void ai_partition(const int* __restrict__ tokens, int n,
                                                    int* __restrict__ cnt,
                                                    int* __restrict__ l0, int* __restrict__ l1) {
    __shared__ int wcnt[4][3];
    __shared__ int wbase[4][3];
    int i = blockIdx.x * blockDim.x + threadIdx.x;
    int lane = threadIdx.x & 63, w = threadIdx.x >> 6;
    int t = (i < n) ? tokens[i] : -1;
    int c = (t < 0) ? 3 : (t >= 20000) ? 1 : (t >= 5000) ? 0 : 2;
    unsigned long long m0 = __ballot(c == 0);
    unsigned long long m1 = __ballot(c == 1);
    unsigned long long m2 = __ballot(c == 2);
    if (lane == 0) { wcnt[w][0] = __popcll(m0); wcnt[w][1] = __popcll(m1); wcnt[w][2] = __popcll(m2); }
    __syncthreads();
    if (threadIdx.x < 3) {
        int j = threadIdx.x;
        int s0 = wcnt[0][j], s1 = wcnt[1][j], s2 = wcnt[2][j], s3 = wcnt[3][j];
        int base = atomicAdd(&cnt[j], s0 + s1 + s2 + s3);
        wbase[0][j] = base; wbase[1][j] = base + s0;
        wbase[2][j] = base + s0 + s1; wbase[3][j] = base + s0 + s1 + s2;
    }
    __syncthreads();
    unsigned long long lt = (1ull << lane) - 1ull;
    if (c == 0)      l0[wbase[w][0] + __popcll(m0 & lt)] = i;
    else if (c == 1) l1[wbase[w][1] + __popcll(m1 & lt)] = i;
    else if (c == 2) l1[n - 1 - (wbase[w][2] + __popcll(m2 & lt))] = i;
}

// Gather + convert + head copy, one streaming kernel (segments sized by device
// counts; 8 floats per item).
__global__ __launch_bounds__(256) void ai_gather_cvt(
    const int* __restrict__ tokens,
    const int* __restrict__ l0, const int* __restrict__ l1,
    const int* __restrict__ cnt, int n,
    const float* __restrict__ e0f, const float* __restrict__ e1f,
    const float* __restrict__ w0f, const float* __restrict__ w1f,
    const float* __restrict__ hef,
    u16* __restrict__ a0p, u16* __restrict__ a1p,
    u16* __restrict__ wb0, u16* __restrict__ wb1,
    float* __restrict__ out)
{
    const int c0 = cnt[0], c1 = cnt[1], hc = cnt[2];
    const int wItems = (1024 * 512 + 1024 * 256) / 8;   // 98304
    const int i1 = wItems + c0 * 64;
    const int i2 = i1 + c1 * 32;
    const int total = i2 + hc * 128;
    for (int i = blockIdx.x * blockDim.x + threadIdx.x; i < total;
         i += gridDim.x * blockDim.x) {
        const float* s; size_t so;
        u16* d; size_t dofs;
        if (i < wItems) {
            int j = i;
            if (j < 65536) { s = w0f; d = wb0; so = (size_t)j * 8; }
            else           { s = w1f; d = wb1; so = (size_t)(j - 65536) * 8; }
            dofs = so;
        } else if (i < i1) {
            int j = i - wItems;
            int m = j >> 6, k8 = j & 63;
            int er = tokens[l0[m]] - 5000;
            s = e0f; d = a0p;
            so = (size_t)er * 512 + k8 * 8;
            dofs = (size_t)m * 512 + k8 * 8;
        } else if (i < i2) {
            int j = i - i1;
            int m = j >> 5, k8 = j & 31;
            int er = tokens[l1[m]] - 20000;
            s = e1f; d = a1p;
            so = (size_t)er * 256 + k8 * 8;
            dofs = (size_t)m * 256 + k8 * 8;
        } else {
            int j = i - i2;
            int m = j >> 7, k8 = j & 127;
            int p = l1[n - 1 - m];
            int t = tokens[p];
            const float4* src = (const float4*)(hef + (size_t)t * 1024 + k8 * 8);
            float4* dst = (float4*)(out + (size_t)p * 1024 + k8 * 8);
            dst[0] = src[0];
            dst[1] = src[1];
            continue;
        }
        float4 a = *(const float4*)(s + so);
        float4 b = *(const float4*)(s + so + 4);
        uint4 q = { pk2bf(a.x, a.y), pk2bf(a.z, a.w), pk2bf(b.x, b.y), pk2bf(b.z, b.w) };
        *(uint4*)(d + dofs) = q;
    }
}

// Merged compacted-A GEMM, z=0: tail0 (K=512), z=1: tail1 (K=256).
// 128M x 256N tile, 512 threads = 8 waves (2M x 4N), wave tile 64x64.
// 3-buffer LDS, 2-deep glds prefetch, counted vmcnt(12/6/0).
__global__ __launch_bounds__(512, 2) void ai_tail_gemm(
    const int* __restrict__ l0, const int* __restrict__ l1,
    const int* __restrict__ cnt,
    const u16* __restrict__ a0p, const u16* __restrict__ a1p,
    const u16* __restrict__ wb0, const u16* __restrict__ wb1,
    float* __restrict__ out)
{
    constexpr int BK = 64;
    __shared__ __align__(16) u16 As[3][128 * BK];   // 48 KB
    __shared__ __align__(16) u16 Bs[3][256 * BK];   // 96 KB
    __shared__ int s_opos[128];

    const int z = blockIdx.z;
    const int K     = z ? 256 : 512;
    const int count = cnt[z];
    const int* list = z ? l1 : l0;
    const u16* ap   = z ? a1p : a0p;
    const u16* wb   = z ? wb1 : wb0;

    // Bijective XCD swizzle: id = [a | n:2 | xcd:3]; m-tile = 8a + xcd, n-tile = n.
    const int id = blockIdx.y * 4 + blockIdx.x;
    const int m0 = (((id >> 5) << 3) | (id & 7)) * 128;
    const int n0 = ((id >> 3) & 3) * 256;
    if (m0 >= count) return;
    const int tid = threadIdx.x;

    const int lane = tid & 63;
    const int wave = tid >> 6;          // 0..7
    const int wm = (wave >> 2) * 64;
    const int wn = (wave & 3) * 64;
    const int fr = lane & 15;
    const int fk = (lane >> 4) * 8;
    const int swzm = (fr & 7) << 4;

    // glds roles: chunk = 8 rows x 64 cols (1 KB). A: 2 chunks/wave; B: 4/wave.
    const int rlc  = lane >> 3;
    const int c16s = (lane & 7) ^ rlc;

    const u16* aSrc[2];
    const u16* bSrc[4];
    #pragma unroll
    for (int i = 0; i < 2; i++) {
        int row = (wave * 2 + i) * 8 + rlc;
        int ar = m0 + row; if (ar >= count) ar = count - 1;   // clamp; masked at write
        aSrc[i] = ap + (size_t)ar * K + c16s * 8;
    }
    #pragma unroll
    for (int i = 0; i < 4; i++) {
        int row = (wave * 4 + i) * 8 + rlc;
        bSrc[i] = wb + (size_t)(n0 + row) * K + c16s * 8;
    }

    auto issue = [&](int kt, int buf) {
        #pragma unroll
        for (int i = 0; i < 2; i++)
            glds16(aSrc[i] + kt, &As[buf][(wave * 2 + i) * 512]);
        #pragma unroll
        for (int i = 0; i < 4; i++)
            glds16(bSrc[i] + kt, &Bs[buf][(wave * 4 + i) * 512]);
    };

    f32x4 acc[4][4];
    #pragma unroll
    for (int i = 0; i < 4; i++)
        #pragma unroll
        for (int j = 0; j < 4; j++)
            acc[i][j] = (f32x4){0.f, 0.f, 0.f, 0.f};

    const int nt = K / BK;              // 8 or 4
    issue(0, 0);                        // overlaps s_opos staging
    if (tid < 128) {
        int m = m0 + tid;
        s_opos[tid] = (m < count) ? list[m] : -1;
    }
    issue(BK, 1);                       // 12 in flight

    auto compute = [&](int buf) {
        const char* Abase = (const char*)&As[buf][0];
        const char* Bbase = (const char*)&Bs[buf][0];
        #pragma unroll
        for (int kk = 0; kk < BK; kk += 32) {
            short8 af[4], bf[4];
            #pragma unroll
            for (int f = 0; f < 4; f++) {
                int ra = wm + f * 16 + fr;
                int rb = wn + f * 16 + fr;
                int cb = ((kk + fk) << 1) ^ swzm;   // ra&7 == rb&7 == fr&7
                af[f] = *(const short8*)(Abase + ra * 128 + cb);
                bf[f] = *(const short8*)(Bbase + rb * 128 + cb);
            }
            #pragma unroll
            for (int i = 0; i < 4; i++)
                #pragma unroll
                for (int j = 0; j < 4; j++)
                    acc[i][j] = __builtin_amdgcn_mfma_f32_16x16x32_bf16(af[i], bf[j], acc[i][j], 0, 0, 0);
        }
    };

    for (int t = 0; t < nt; t++) {
        const int cur = t % 3;
        if (t + 2 < nt) {
            issue((t + 2) * BK, (t + 2) % 3);                 // 18 in flight
            asm volatile("s_waitcnt vmcnt(12)" ::: "memory"); // buf[cur]'s 6 done
        } else if (t + 1 < nt) {
            asm volatile("s_waitcnt vmcnt(6)" ::: "memory");  // drain: buf[cur] done
        } else {
            asm volatile("s_waitcnt vmcnt(0)" ::: "memory");
        }
        __builtin_amdgcn_s_barrier();                         // buf[cur] ready for all
        __builtin_amdgcn_s_setprio(1);
        compute(cur);
        __builtin_amdgcn_s_setprio(0);
        asm volatile("" ::: "memory");                        // keep ds_reads above
        __builtin_amdgcn_s_barrier();                         // WAR before buf reuse
    }

    // epilogue: C/D layout col = lane&15, row = (lane>>4)*4 + reg  [m89/m91]
    const int rbase = (lane >> 4) * 4;
    #pragma unroll
    for (int i = 0; i < 4; i++) {
        #pragma unroll
        for (int r = 0; r < 4; r++) {
            int ml = wm + i * 16 + rbase + r;
            if (m0 + ml < count) {
                float* orow = out + (size_t)s_opos[ml] * 1024 + n0 + wn + fr;
                orow[0]  = acc[i][0][r];
                orow[16] = acc[i][1][r];
                orow[32] = acc[i][2][r];
                orow[48] = acc[i][3][r];
            }
        }
    }
}

// Fallback if ws is too small (not expected). Slow exact fp32.
__global__ __launch_bounds__(256) void ai_naive(
    const int* __restrict__ tokens,
    const float* __restrict__ he,
    const float* __restrict__ e0, const float* __restrict__ w0,
    const float* __restrict__ e1, const float* __restrict__ w1,
    float* __restrict__ out)
{
    int p = blockIdx.x;
    int t = tokens[p];
    float* o = out + (size_t)p * 1024;
    if (t < 5000) {
        for (int j = threadIdx.x; j < 1024; j += 256) o[j] = he[(size_t)t * 1024 + j];
    } else if (t < 20000) {
        const float* e = e0 + (size_t)(t - 5000) * 512;
        for (int j = threadIdx.x; j < 1024; j += 256) {
            float s = 0.f;
            const float* wr = w0 + (size_t)j * 512;
            for (int k = 0; k < 512; k++) s += e[k] * wr[k];
            o[j] = s;
        }
    } else {
        const float* e = e1 + (size_t)(t - 20000) * 256;
        for (int j = threadIdx.x; j < 1024; j += 256) {
            float s = 0.f;
            const float* wr = w1 + (size_t)j * 256;
            for (int k = 0; k < 256; k++) s += e[k] * wr[k];
            o[j] = s;
        }
    }
}

extern "C" void kernel_launch(void* const* d_in, const int* in_sizes, int n_in,
                              void* d_out, int out_size, void* d_ws, size_t ws_size,
                              hipStream_t stream) {
    const int*   tokens   = (const int*)d_in[0];
    const float* head_emb = (const float*)d_in[1];
    const float* t0_emb   = (const float*)d_in[2];
    const float* t0_w     = (const float*)d_in[3];
    const float* t1_emb   = (const float*)d_in[4];
    const float* t1_w     = (const float*)d_in[5];
    float* out = (float*)d_out;
    const int N = in_sizes[0];          // 32768
    const int nW0 = in_sizes[3];        // 1024*512
    const int nW1 = in_sizes[5];        // 1024*256

    // ws: cnt[16] | l0[N] | l1[N] | Wb0 | Wb1 | A0'[N*512] | A1'[N*256]   (bf16)
    int* cnt = (int*)d_ws;
    int* l0  = cnt + 16;
    int* l1  = l0 + N;
    size_t base_need = 64 + (size_t)2 * N * 4;
    size_t need = base_need + ((size_t)nW0 + nW1 + (size_t)N * 512 + (size_t)N * 256) * 2;
    if (ws_size < need) {
        ai_naive<<<N, 256, 0, stream>>>(tokens, head_emb, t0_emb, t0_w, t1_emb, t1_w, out);
        return;
    }
    u16* wb0 = (u16*)((char*)d_ws + base_need);
    u16* wb1 = wb0 + nW0;
    u16* a0p = wb1 + nW1;
    u16* a1p = a0p + (size_t)N * 512;

    hipMemsetAsync(cnt, 0, 64, stream);
    ai_partition<<<(N + 255) / 256, 256, 0, stream>>>(tokens, N, cnt, l0, l1);
    ai_gather_cvt<<<2048, 256, 0, stream>>>(tokens, l0, l1, cnt, N,
                                            t0_emb, t1_emb, t0_w, t1_w, head_emb,
                                            a0p, a1p, wb0, wb1, out);

    dim3 g(4, (N + 127) / 128, 2);   // y padded: bijective swizzle needs y*4 ids
    ai_tail_gemm<<<g, 512, 0, stream>>>(l0, l1, cnt, a0p, a1p, wb0, wb1, out);
}